// Round 1
// baseline (1124.309 us; speedup 1.0000x reference)
//
#include <hip/hip_runtime.h>
#include <hip/hip_bf16.h>

#define B_ 32768
#define S_ 3
#define L_ 5
#define D1 32
#define D2 64
#define OUT_N 541
#define OUT_PAD 576
#define KDIM 320   // D2*L
#define EPS_ 1e-5f

typedef __attribute__((ext_vector_type(8))) short bf16x8;
typedef __attribute__((ext_vector_type(4))) float f32x4;

__device__ __forceinline__ float gelu_exact(float v) {
    return 0.5f * v * (1.0f + erff(v * 0.70710678118654752440f));
}

// ---------------------------------------------------------------------------
// Kernel 1: per-(b,s) conv1 -> gelu -> conv2 -> gelu; write bf16 H rows;
// accumulate per-channel sum/sumsq for BN (wave reduce + global atomics).
// ---------------------------------------------------------------------------
__global__ __launch_bounds__(128) void k_feat(
    const float* __restrict__ x, const float* __restrict__ w1, const float* __restrict__ b1,
    const float* __restrict__ w2, const float* __restrict__ b2,
    __hip_bfloat16* __restrict__ H, float* __restrict__ stats)
{
    const int s = blockIdx.y;
    const int b = blockIdx.x * 128 + (int)threadIdx.x;

    __shared__ float sw1[D1 * 3];
    __shared__ float sb1[D1];
    __shared__ float sw2[D2 * D1 * 3];
    __shared__ float sb2[D2];
    for (int i = threadIdx.x; i < D1 * 3; i += 128) sw1[i] = w1[s * D1 * 3 + i];
    for (int i = threadIdx.x; i < D1; i += 128)     sb1[i] = b1[s * D1 + i];
    for (int i = threadIdx.x; i < D2 * D1 * 3; i += 128) sw2[i] = w2[s * D2 * D1 * 3 + i];
    for (int i = threadIdx.x; i < D2; i += 128)     sb2[i] = b2[s * D2 + i];
    __syncthreads();

    // load x row (padded)
    float xv[L_ + 2];
    xv[0] = 0.f; xv[L_ + 1] = 0.f;
    const float* xp = x + ((size_t)b * S_ + s) * L_;
#pragma unroll
    for (int l = 0; l < L_; ++l) xv[l + 1] = xp[l];

    // conv1 + gelu -> h1 in registers (compile-time indexed)
    float h1[D1][L_];
#pragma unroll
    for (int c = 0; c < D1; ++c) {
        const float wa = sw1[c * 3 + 0], wb = sw1[c * 3 + 1], wc = sw1[c * 3 + 2], bb = sb1[c];
#pragma unroll
        for (int l = 0; l < L_; ++l) {
            float xm = (l == 0) ? xv[0] : xv[l];       // xv is already padded: indices l, l+1, l+2
            float v = wa * xv[l] + wb * xv[l + 1] + wc * xv[l + 2] + bb;
            (void)xm;
            h1[c][l] = gelu_exact(v);
        }
    }

    __hip_bfloat16* hrow = H + ((size_t)s * B_ + b) * KDIM;

    for (int c2 = 0; c2 < D2; ++c2) {
        const float bb = sb2[c2];
        float a0 = bb, a1 = bb, a2 = bb, a3 = bb, a4 = bb;
        const float* wr = &sw2[c2 * D1 * 3];
#pragma unroll
        for (int c1 = 0; c1 < D1; ++c1) {
            const float wa = wr[c1 * 3 + 0], wb = wr[c1 * 3 + 1], wc = wr[c1 * 3 + 2];
            const float p0 = h1[c1][0], p1 = h1[c1][1], p2 = h1[c1][2], p3 = h1[c1][3], p4 = h1[c1][4];
            a0 += wb * p0 + wc * p1;               // left edge: x[-1]=0
            a1 += wa * p0 + wb * p1 + wc * p2;
            a2 += wa * p1 + wb * p2 + wc * p3;
            a3 += wa * p2 + wb * p3 + wc * p4;
            a4 += wa * p3 + wb * p4;               // right edge: x[5]=0
        }
        const float g0 = gelu_exact(a0), g1 = gelu_exact(a1), g2 = gelu_exact(a2),
                    g3 = gelu_exact(a3), g4 = gelu_exact(a4);
        hrow[c2 * L_ + 0] = __float2bfloat16(g0);
        hrow[c2 * L_ + 1] = __float2bfloat16(g1);
        hrow[c2 * L_ + 2] = __float2bfloat16(g2);
        hrow[c2 * L_ + 3] = __float2bfloat16(g3);
        hrow[c2 * L_ + 4] = __float2bfloat16(g4);

        float su = g0 + g1 + g2 + g3 + g4;
        float sq = g0 * g0 + g1 * g1 + g2 * g2 + g3 * g3 + g4 * g4;
#pragma unroll
        for (int off = 32; off > 0; off >>= 1) {
            su += __shfl_down(su, off);
            sq += __shfl_down(sq, off);
        }
        if ((threadIdx.x & 63) == 0) {
            atomicAdd(&stats[(s * D2 + c2) * 2 + 0], su);
            atomicAdd(&stats[(s * D2 + c2) * 2 + 1], sq);
        }
    }
}

// ---------------------------------------------------------------------------
// Kernel 2a: finalize BN stats -> per-channel scale a and shift c
// ---------------------------------------------------------------------------
__global__ void k_stats(const float* __restrict__ stats,
                        const float* __restrict__ gamma, const float* __restrict__ beta,
                        float* __restrict__ af, float* __restrict__ cf)
{
    int i = threadIdx.x;
    if (i < S_ * D2) {
        const float n = (float)B_ * (float)L_;
        float su = stats[i * 2 + 0], sq = stats[i * 2 + 1];
        float mean = su / n;
        float var = sq / n - mean * mean;
        float rstd = rsqrtf(var + EPS_);
        float a = gamma[i] * rstd;
        af[i] = a;
        cf[i] = beta[i] - mean * a;
    }
}

// ---------------------------------------------------------------------------
// Kernel 2b: fold BN into linear weights (bf16, padded to OUT_PAD rows)
// ---------------------------------------------------------------------------
__global__ void k_fold(const float* __restrict__ wl, const float* __restrict__ bl,
                       const float* __restrict__ af, const float* __restrict__ cf,
                       __hip_bfloat16* __restrict__ Wp, float* __restrict__ blp)
{
    int t = blockIdx.x * blockDim.x + (int)threadIdx.x;
    if (t >= S_ * OUT_PAD) return;
    int s = t / OUT_PAD, o = t % OUT_PAD;
    __hip_bfloat16* wrow = Wp + ((size_t)s * OUT_PAD + o) * KDIM;
    if (o >= OUT_N) {
        for (int k = 0; k < KDIM; ++k) wrow[k] = __float2bfloat16(0.f);
        blp[s * OUT_PAD + o] = 0.f;
        return;
    }
    const float* wsrc = wl + ((size_t)s * OUT_N + o) * KDIM;
    float bacc = bl[s * OUT_N + o];
    for (int k = 0; k < KDIM; ++k) {
        float wv = wsrc[k];
        int c = k / L_;
        wrow[k] = __float2bfloat16(wv * af[s * D2 + c]);
        bacc += wv * cf[s * D2 + c];
    }
    blp[s * OUT_PAD + o] = bacc;
}

// ---------------------------------------------------------------------------
// Kernel 3: bf16 MFMA GEMM  C[M=B, N=OUT] = H[M,K] * Wp[N,K]^T + blp
// block = 256 (4 waves), tile 128(M) x 64(N); wave = 32x64 via 2x4 MFMA tiles
// ---------------------------------------------------------------------------
__global__ __launch_bounds__(256) void k_gemm(
    const __hip_bfloat16* __restrict__ H, const __hip_bfloat16* __restrict__ Wp,
    const float* __restrict__ blp, float* __restrict__ out)
{
    const int s    = blockIdx.z;
    const int bm   = blockIdx.x * 128;
    const int bn   = blockIdx.y * 64;
    const int wave = threadIdx.x >> 6;
    const int lane = threadIdx.x & 63;
    const int lm   = lane & 15;
    const int quad = lane >> 4;

    const short* A  = (const short*)(H  + ((size_t)s * B_ + bm + wave * 32) * KDIM) + quad * 8;
    const short* Bp = (const short*)(Wp + ((size_t)s * OUT_PAD + bn) * KDIM) + quad * 8;

    f32x4 acc[2][4];
#pragma unroll
    for (int i = 0; i < 2; ++i)
#pragma unroll
        for (int j = 0; j < 4; ++j) acc[i][j] = (f32x4){0.f, 0.f, 0.f, 0.f};

#pragma unroll 2
    for (int k = 0; k < KDIM; k += 32) {
        bf16x8 a0 = *(const bf16x8*)(A + (size_t)(lm)      * KDIM + k);
        bf16x8 a1 = *(const bf16x8*)(A + (size_t)(16 + lm) * KDIM + k);
        bf16x8 b0 = *(const bf16x8*)(Bp + (size_t)(lm)      * KDIM + k);
        bf16x8 b1 = *(const bf16x8*)(Bp + (size_t)(16 + lm) * KDIM + k);
        bf16x8 b2 = *(const bf16x8*)(Bp + (size_t)(32 + lm) * KDIM + k);
        bf16x8 b3 = *(const bf16x8*)(Bp + (size_t)(48 + lm) * KDIM + k);
        acc[0][0] = __builtin_amdgcn_mfma_f32_16x16x32_bf16(a0, b0, acc[0][0], 0, 0, 0);
        acc[0][1] = __builtin_amdgcn_mfma_f32_16x16x32_bf16(a0, b1, acc[0][1], 0, 0, 0);
        acc[0][2] = __builtin_amdgcn_mfma_f32_16x16x32_bf16(a0, b2, acc[0][2], 0, 0, 0);
        acc[0][3] = __builtin_amdgcn_mfma_f32_16x16x32_bf16(a0, b3, acc[0][3], 0, 0, 0);
        acc[1][0] = __builtin_amdgcn_mfma_f32_16x16x32_bf16(a1, b0, acc[1][0], 0, 0, 0);
        acc[1][1] = __builtin_amdgcn_mfma_f32_16x16x32_bf16(a1, b1, acc[1][1], 0, 0, 0);
        acc[1][2] = __builtin_amdgcn_mfma_f32_16x16x32_bf16(a1, b2, acc[1][2], 0, 0, 0);
        acc[1][3] = __builtin_amdgcn_mfma_f32_16x16x32_bf16(a1, b3, acc[1][3], 0, 0, 0);
    }

#pragma unroll
    for (int nt = 0; nt < 4; ++nt) {
        const int col = bn + nt * 16 + lm;
        const float bias = blp[s * OUT_PAD + col];
        if (col < OUT_N) {
#pragma unroll
            for (int mt = 0; mt < 2; ++mt) {
                const int row0 = bm + wave * 32 + mt * 16 + quad * 4;
#pragma unroll
                for (int r = 0; r < 4; ++r) {
                    out[((size_t)(row0 + r) * S_ + s) * OUT_N + col] = acc[mt][nt][r] + bias;
                }
            }
        }
    }
}

// ---------------------------------------------------------------------------
extern "C" void kernel_launch(void* const* d_in, const int* in_sizes, int n_in,
                              void* d_out, int out_size, void* d_ws, size_t ws_size,
                              hipStream_t stream) {
    const float* x     = (const float*)d_in[0];
    const float* w1    = (const float*)d_in[1];
    const float* b1    = (const float*)d_in[2];
    const float* w2    = (const float*)d_in[3];
    const float* b2    = (const float*)d_in[4];
    const float* gamma = (const float*)d_in[5];
    const float* beta  = (const float*)d_in[6];
    const float* wl    = (const float*)d_in[7];
    const float* bl    = (const float*)d_in[8];
    float* out = (float*)d_out;

    char* ws = (char*)d_ws;
    __hip_bfloat16* H = (__hip_bfloat16*)ws;                       // S*B*KDIM bf16
    size_t offH = (size_t)S_ * B_ * KDIM * sizeof(__hip_bfloat16); // 62,914,560
    float* stats = (float*)(ws + offH);                            // S*D2*2 f32
    float* af = stats + S_ * D2 * 2;                               // S*D2
    float* cf = af + S_ * D2;                                      // S*D2
    __hip_bfloat16* Wp = (__hip_bfloat16*)(cf + S_ * D2);          // S*OUT_PAD*KDIM bf16
    float* blp = (float*)((char*)Wp + (size_t)S_ * OUT_PAD * KDIM * sizeof(__hip_bfloat16));

    hipMemsetAsync(stats, 0, (size_t)S_ * D2 * 2 * sizeof(float), stream);

    k_feat<<<dim3(B_ / 128, S_), 128, 0, stream>>>(x, w1, b1, w2, b2, H, stats);
    k_stats<<<1, 256, 0, stream>>>(stats, gamma, beta, af, cf);
    k_fold<<<(S_ * OUT_PAD + 255) / 256, 256, 0, stream>>>(wl, bl, af, cf, Wp, blp);
    k_gemm<<<dim3(B_ / 128, OUT_PAD / 64, S_), 256, 0, stream>>>(H, Wp, blp, out);
}

// Round 2
// 558.985 us; speedup vs baseline: 2.0113x; 2.0113x over previous
//
#include <hip/hip_runtime.h>
#include <hip/hip_bf16.h>

#define B_ 32768
#define S_ 3
#define L_ 5
#define D1 32
#define D2 64
#define OUT_N 541
#define OUT_PAD 576
#define KDIM 320   // D2*L
#define EPS_ 1e-5f

typedef __attribute__((ext_vector_type(8))) short bf16x8;
typedef __attribute__((ext_vector_type(4))) float f32x4;

__device__ __forceinline__ short f2bf(float f) {
    __hip_bfloat16 h = __float2bfloat16(f);
    return *reinterpret_cast<short*>(&h);
}
__device__ __forceinline__ float bf2f(short u) {
    union { float f; unsigned v; } x;
    x.v = ((unsigned)(unsigned short)u) << 16;
    return x.f;
}

// tanh-form GELU: x * sigmoid(1.5957691216*x + 0.0713548162*x^3)
// max abs deviation from exact-erf gelu ~3e-4 — negligible vs bf16 noise.
__device__ __forceinline__ float gelu_fast(float x) {
    float x2 = x * x;
    float u = x * fmaf(x2, -0.0713548162726f, -1.59576912161f); // -2z
    float e = __expf(u);
    float r = __builtin_amdgcn_rcpf(1.0f + e);
    return x * r;
}

// ---------------------------------------------------------------------------
// Kernel 1 v2: block = 256 threads = 32 b-values x 8 "ci" slots, one s.
// Phase 1: thread (bi,ci) computes h1 channels [ci*4, ci*4+4) -> LDS (bf16).
// Phase 2: thread (bi,ci) computes h2 channels [ci*8, ci*8+8) -> global H,
//          plus per-channel sum/sumsq reduced to global atomics.
// ---------------------------------------------------------------------------
__global__ __launch_bounds__(256, 3) void k_feat(
    const float* __restrict__ x, const float* __restrict__ w1, const float* __restrict__ b1,
    const float* __restrict__ w2, const float* __restrict__ b2,
    __hip_bfloat16* __restrict__ H, float* __restrict__ stats)
{
    const int s   = blockIdx.y;
    const int tid = threadIdx.x;
    const int ci  = tid & 7;
    const int bi  = tid >> 3;
    const int b   = blockIdx.x * 32 + bi;

    __shared__ __align__(16) float sw1[D1 * 3];
    __shared__ float sb1[D1];
    __shared__ __align__(16) float sw2T[D1 * 3 * D2];   // [c1][dl][c2]
    __shared__ float sb2[D2];
    __shared__ __align__(16) short sh1[32 * 264];       // [bi][c1*8], stride 264 shorts (528B)
    __shared__ float sred[4][8][16];

    for (int i = tid; i < D1 * 3; i += 256) sw1[i] = w1[s * D1 * 3 + i];
    for (int i = tid; i < D1; i += 256)     sb1[i] = b1[s * D1 + i];
    for (int i = tid; i < D2; i += 256)     sb2[i] = b2[s * D2 + i];
    for (int i = tid; i < D1 * 3 * D2; i += 256) {
        int c2 = i & 63, t = i >> 6;
        int dl = t % 3, c1 = t / 3;
        sw2T[i] = w2[((size_t)(s * D2 + c2) * D1 + c1) * 3 + dl];
    }
    __syncthreads();

    // ---- Phase 1: conv1 + gelu for 4 channels of this bi ----
    float xv[L_ + 2];
    xv[0] = 0.f; xv[L_ + 1] = 0.f;
    const float* xp = x + (size_t)b * (S_ * L_) + s * L_;
#pragma unroll
    for (int l = 0; l < L_; ++l) xv[l + 1] = xp[l];

#pragma unroll
    for (int k = 0; k < 4; ++k) {
        const int c1 = ci * 4 + k;
        const float wa = sw1[c1 * 3 + 0], wb = sw1[c1 * 3 + 1], wc = sw1[c1 * 3 + 2];
        const float bb = sb1[c1];
        bf16x8 pk;
#pragma unroll
        for (int l = 0; l < L_; ++l) {
            float v = fmaf(wa, xv[l], fmaf(wb, xv[l + 1], fmaf(wc, xv[l + 2], bb)));
            pk[l] = f2bf(gelu_fast(v));
        }
        pk[5] = 0; pk[6] = 0; pk[7] = 0;
        *(bf16x8*)&sh1[bi * 264 + c1 * 8] = pk;
    }
    __syncthreads();

    // ---- Phase 2: conv2 + gelu for 8 channels c2 = ci*8 + j ----
    float acc[8][5];
#pragma unroll
    for (int j = 0; j < 8; ++j) {
        const float bb = sb2[ci * 8 + j];
#pragma unroll
        for (int l = 0; l < 5; ++l) acc[j][l] = bb;
    }

#pragma unroll 2
    for (int c1 = 0; c1 < D1; ++c1) {
        bf16x8 hv = *(const bf16x8*)&sh1[bi * 264 + c1 * 8];
        const float p0 = bf2f(hv[0]), p1 = bf2f(hv[1]), p2 = bf2f(hv[2]),
                    p3 = bf2f(hv[3]), p4 = bf2f(hv[4]);
        const float* wbase = &sw2T[c1 * 3 * 64 + ci * 8];
        f32x4 w0a = *(const f32x4*)(wbase + 0 * 64);
        f32x4 w0b = *(const f32x4*)(wbase + 0 * 64 + 4);
        f32x4 w1a = *(const f32x4*)(wbase + 1 * 64);
        f32x4 w1b = *(const f32x4*)(wbase + 1 * 64 + 4);
        f32x4 w2a = *(const f32x4*)(wbase + 2 * 64);
        f32x4 w2b = *(const f32x4*)(wbase + 2 * 64 + 4);
#pragma unroll
        for (int j = 0; j < 8; ++j) {
            const float wA = (j < 4) ? w0a[j & 3] : w0b[j & 3];
            const float wB = (j < 4) ? w1a[j & 3] : w1b[j & 3];
            const float wC = (j < 4) ? w2a[j & 3] : w2b[j & 3];
            acc[j][0] = fmaf(wB, p0, fmaf(wC, p1, acc[j][0]));
            acc[j][1] = fmaf(wA, p0, fmaf(wB, p1, fmaf(wC, p2, acc[j][1])));
            acc[j][2] = fmaf(wA, p1, fmaf(wB, p2, fmaf(wC, p3, acc[j][2])));
            acc[j][3] = fmaf(wA, p2, fmaf(wB, p3, fmaf(wC, p4, acc[j][3])));
            acc[j][4] = fmaf(wA, p3, fmaf(wB, p4, acc[j][4]));
        }
    }

    // gelu, quantize, stats, store
    bf16x8 hbv[5];
    float su[8], sq[8];
#pragma unroll
    for (int j = 0; j < 8; ++j) { su[j] = 0.f; sq[j] = 0.f; }
#pragma unroll
    for (int t = 0; t < 5; ++t) {
#pragma unroll
        for (int e = 0; e < 8; ++e) {
            const int idx = t * 8 + e;
            const int j = idx / 5, l = idx % 5;
            float g = gelu_fast(acc[j][l]);
            short hb = f2bf(g);
            hbv[t][e] = hb;
            float gq = bf2f(hb);
            su[j] += gq;
            sq[j] = fmaf(gq, gq, sq[j]);
        }
    }
    bf16x8* dst = (bf16x8*)(H + ((size_t)s * B_ + b) * KDIM + ci * 40);
#pragma unroll
    for (int t = 0; t < 5; ++t) dst[t] = hbv[t];

    // reduce su/sq across the 8 bi groups within the wave
#pragma unroll
    for (int j = 0; j < 8; ++j) {
        su[j] += __shfl_down(su[j], 32); sq[j] += __shfl_down(sq[j], 32);
        su[j] += __shfl_down(su[j], 16); sq[j] += __shfl_down(sq[j], 16);
        su[j] += __shfl_down(su[j], 8);  sq[j] += __shfl_down(sq[j], 8);
    }
    const int wid = tid >> 6;
    const int lane = tid & 63;
    if (lane < 8) {
#pragma unroll
        for (int j = 0; j < 8; ++j) {
            sred[wid][lane][j] = su[j];
            sred[wid][lane][8 + j] = sq[j];
        }
    }
    __syncthreads();
    if (tid < 128) {
        const int which = tid >> 6;     // 0 = sum, 1 = sumsq
        const int c2 = tid & 63;
        const int rci = c2 >> 3, rj = c2 & 7;
        float v = sred[0][rci][which * 8 + rj] + sred[1][rci][which * 8 + rj]
                + sred[2][rci][which * 8 + rj] + sred[3][rci][which * 8 + rj];
        atomicAdd(&stats[(s * D2 + c2) * 2 + which], v);
    }
}

// ---------------------------------------------------------------------------
// Kernel 2a: finalize BN stats -> per-channel scale a and shift c
// ---------------------------------------------------------------------------
__global__ void k_stats(const float* __restrict__ stats,
                        const float* __restrict__ gamma, const float* __restrict__ beta,
                        float* __restrict__ af, float* __restrict__ cf)
{
    int i = threadIdx.x;
    if (i < S_ * D2) {
        const float n = (float)B_ * (float)L_;
        float su = stats[i * 2 + 0], sq = stats[i * 2 + 1];
        float mean = su / n;
        float var = sq / n - mean * mean;
        float rstd = rsqrtf(var + EPS_);
        float a = gamma[i] * rstd;
        af[i] = a;
        cf[i] = beta[i] - mean * a;
    }
}

// ---------------------------------------------------------------------------
// Kernel 2b v2: fold BN into linear weights — one wave per output row.
// KDIM = 320 = 64 lanes * 5, and k/5 == lane, so lane <-> channel exactly.
// ---------------------------------------------------------------------------
__global__ __launch_bounds__(64) void k_fold(
    const float* __restrict__ wl, const float* __restrict__ bl,
    const float* __restrict__ af, const float* __restrict__ cf,
    __hip_bfloat16* __restrict__ Wp, float* __restrict__ blp)
{
    const int row = blockIdx.x;            // 0 .. S_*OUT_PAD-1
    const int s = row / OUT_PAD, o = row % OUT_PAD;
    const int lane = threadIdx.x;
    __hip_bfloat16* wrow = Wp + (size_t)row * KDIM;
    if (o >= OUT_N) {
#pragma unroll
        for (int t = 0; t < 5; ++t) wrow[lane * 5 + t] = __float2bfloat16(0.f);
        if (lane == 0) blp[row] = 0.f;
        return;
    }
    const float* wsrc = wl + ((size_t)s * OUT_N + o) * KDIM;
    const float a = af[s * D2 + lane];
    const float c = cf[s * D2 + lane];
    float bacc = 0.f;
#pragma unroll
    for (int t = 0; t < 5; ++t) {
        float wv = wsrc[lane * 5 + t];
        wrow[lane * 5 + t] = __float2bfloat16(wv * a);
        bacc = fmaf(wv, c, bacc);
    }
#pragma unroll
    for (int off = 32; off > 0; off >>= 1) bacc += __shfl_down(bacc, off);
    if (lane == 0) blp[row] = bacc + bl[s * OUT_N + o];
}

// ---------------------------------------------------------------------------
// Kernel 3: bf16 MFMA GEMM  C[M=B, N=OUT] = H[M,K] * Wp[N,K]^T + blp
// ---------------------------------------------------------------------------
__global__ __launch_bounds__(256) void k_gemm(
    const __hip_bfloat16* __restrict__ H, const __hip_bfloat16* __restrict__ Wp,
    const float* __restrict__ blp, float* __restrict__ out)
{
    const int s    = blockIdx.z;
    const int bm   = blockIdx.x * 128;
    const int bn   = blockIdx.y * 64;
    const int wave = threadIdx.x >> 6;
    const int lane = threadIdx.x & 63;
    const int lm   = lane & 15;
    const int quad = lane >> 4;

    const short* A  = (const short*)(H  + ((size_t)s * B_ + bm + wave * 32) * KDIM) + quad * 8;
    const short* Bp = (const short*)(Wp + ((size_t)s * OUT_PAD + bn) * KDIM) + quad * 8;

    f32x4 acc[2][4];
#pragma unroll
    for (int i = 0; i < 2; ++i)
#pragma unroll
        for (int j = 0; j < 4; ++j) acc[i][j] = (f32x4){0.f, 0.f, 0.f, 0.f};

#pragma unroll 2
    for (int k = 0; k < KDIM; k += 32) {
        bf16x8 a0 = *(const bf16x8*)(A + (size_t)(lm)      * KDIM + k);
        bf16x8 a1 = *(const bf16x8*)(A + (size_t)(16 + lm) * KDIM + k);
        bf16x8 b0 = *(const bf16x8*)(Bp + (size_t)(lm)      * KDIM + k);
        bf16x8 b1 = *(const bf16x8*)(Bp + (size_t)(16 + lm) * KDIM + k);
        bf16x8 b2 = *(const bf16x8*)(Bp + (size_t)(32 + lm) * KDIM + k);
        bf16x8 b3 = *(const bf16x8*)(Bp + (size_t)(48 + lm) * KDIM + k);
        acc[0][0] = __builtin_amdgcn_mfma_f32_16x16x32_bf16(a0, b0, acc[0][0], 0, 0, 0);
        acc[0][1] = __builtin_amdgcn_mfma_f32_16x16x32_bf16(a0, b1, acc[0][1], 0, 0, 0);
        acc[0][2] = __builtin_amdgcn_mfma_f32_16x16x32_bf16(a0, b2, acc[0][2], 0, 0, 0);
        acc[0][3] = __builtin_amdgcn_mfma_f32_16x16x32_bf16(a0, b3, acc[0][3], 0, 0, 0);
        acc[1][0] = __builtin_amdgcn_mfma_f32_16x16x32_bf16(a1, b0, acc[1][0], 0, 0, 0);
        acc[1][1] = __builtin_amdgcn_mfma_f32_16x16x32_bf16(a1, b1, acc[1][1], 0, 0, 0);
        acc[1][2] = __builtin_amdgcn_mfma_f32_16x16x32_bf16(a1, b2, acc[1][2], 0, 0, 0);
        acc[1][3] = __builtin_amdgcn_mfma_f32_16x16x32_bf16(a1, b3, acc[1][3], 0, 0, 0);
    }

#pragma unroll
    for (int nt = 0; nt < 4; ++nt) {
        const int col = bn + nt * 16 + lm;
        const float bias = blp[s * OUT_PAD + col];
        if (col < OUT_N) {
#pragma unroll
            for (int mt = 0; mt < 2; ++mt) {
                const int row0 = bm + wave * 32 + mt * 16 + quad * 4;
#pragma unroll
                for (int r = 0; r < 4; ++r) {
                    out[((size_t)(row0 + r) * S_ + s) * OUT_N + col] = acc[mt][nt][r] + bias;
                }
            }
        }
    }
}

// ---------------------------------------------------------------------------
extern "C" void kernel_launch(void* const* d_in, const int* in_sizes, int n_in,
                              void* d_out, int out_size, void* d_ws, size_t ws_size,
                              hipStream_t stream) {
    const float* x     = (const float*)d_in[0];
    const float* w1    = (const float*)d_in[1];
    const float* b1    = (const float*)d_in[2];
    const float* w2    = (const float*)d_in[3];
    const float* b2    = (const float*)d_in[4];
    const float* gamma = (const float*)d_in[5];
    const float* beta  = (const float*)d_in[6];
    const float* wl    = (const float*)d_in[7];
    const float* bl    = (const float*)d_in[8];
    float* out = (float*)d_out;

    char* ws = (char*)d_ws;
    __hip_bfloat16* H = (__hip_bfloat16*)ws;                       // S*B*KDIM bf16
    size_t offH = (size_t)S_ * B_ * KDIM * sizeof(__hip_bfloat16);
    float* stats = (float*)(ws + offH);                            // S*D2*2 f32
    float* af = stats + S_ * D2 * 2;
    float* cf = af + S_ * D2;
    __hip_bfloat16* Wp = (__hip_bfloat16*)(cf + S_ * D2);          // S*OUT_PAD*KDIM bf16
    float* blp = (float*)((char*)Wp + (size_t)S_ * OUT_PAD * KDIM * sizeof(__hip_bfloat16));

    hipMemsetAsync(stats, 0, (size_t)S_ * D2 * 2 * sizeof(float), stream);

    k_feat<<<dim3(B_ / 32, S_), 256, 0, stream>>>(x, w1, b1, w2, b2, H, stats);
    k_stats<<<1, 256, 0, stream>>>(stats, gamma, beta, af, cf);
    k_fold<<<S_ * OUT_PAD, 64, 0, stream>>>(wl, bl, af, cf, Wp, blp);
    k_gemm<<<dim3(B_ / 128, OUT_PAD / 64, S_), 256, 0, stream>>>(H, Wp, blp, out);
}

// Round 3
// 536.715 us; speedup vs baseline: 2.0948x; 1.0415x over previous
//
#include <hip/hip_runtime.h>
#include <hip/hip_bf16.h>

#define B_ 32768
#define S_ 3
#define L_ 5
#define D1 32
#define D2 64
#define OUT_N 541
#define OUT_PAD 576
#define KDIM 320   // D2*L
#define EPS_ 1e-5f

typedef __attribute__((ext_vector_type(8))) short bf16x8;
typedef __attribute__((ext_vector_type(4))) float f32x4;

__device__ __forceinline__ short f2bf(float f) {
    __hip_bfloat16 h = __float2bfloat16(f);
    return *reinterpret_cast<short*>(&h);
}
__device__ __forceinline__ float bf2f(short u) {
    union { float f; unsigned v; } x;
    x.v = ((unsigned)(unsigned short)u) << 16;
    return x.f;
}

// tanh-form GELU: max abs deviation from exact-erf gelu ~3e-4.
__device__ __forceinline__ float gelu_fast(float x) {
    float x2 = x * x;
    float u = x * fmaf(x2, -0.0713548162726f, -1.59576912161f); // -2z
    float e = __expf(u);
    float r = __builtin_amdgcn_rcpf(1.0f + e);
    return x * r;
}

// async 16B global -> LDS
__device__ __forceinline__ void cp16(void* lds, const void* g) {
    __builtin_amdgcn_global_load_lds(
        (const __attribute__((address_space(1))) unsigned int*)g,
        (__attribute__((address_space(3))) unsigned int*)lds, 16, 0, 0);
}

// ---------------------------------------------------------------------------
// Kernel 1: block = 256 threads = 32 b-values x 8 "ci" slots, one s.
// ---------------------------------------------------------------------------
__global__ __launch_bounds__(256, 3) void k_feat(
    const float* __restrict__ x, const float* __restrict__ w1, const float* __restrict__ b1,
    const float* __restrict__ w2, const float* __restrict__ b2,
    __hip_bfloat16* __restrict__ H, float* __restrict__ stats)
{
    const int s   = blockIdx.y;
    const int tid = threadIdx.x;
    const int ci  = tid & 7;
    const int bi  = tid >> 3;
    const int b   = blockIdx.x * 32 + bi;

    __shared__ __align__(16) float sw1[D1 * 3];
    __shared__ float sb1[D1];
    __shared__ __align__(16) float sw2T[D1 * 3 * D2];   // [c1][dl][c2]
    __shared__ float sb2[D2];
    __shared__ __align__(16) short sh1[32 * 264];       // [bi][c1*8]
    __shared__ float sred[4][8][16];

    // hoist x loads: overlap global latency with LDS weight staging
    float xv[L_ + 2];
    xv[0] = 0.f; xv[L_ + 1] = 0.f;
    const float* xp = x + (size_t)b * (S_ * L_) + s * L_;
#pragma unroll
    for (int l = 0; l < L_; ++l) xv[l + 1] = xp[l];

    for (int i = tid; i < D1 * 3; i += 256) sw1[i] = w1[s * D1 * 3 + i];
    for (int i = tid; i < D1; i += 256)     sb1[i] = b1[s * D1 + i];
    for (int i = tid; i < D2; i += 256)     sb2[i] = b2[s * D2 + i];
    for (int i = tid; i < D1 * 3 * D2; i += 256) {
        int c2 = i & 63, t = i >> 6;
        int dl = t % 3, c1 = t / 3;
        sw2T[i] = w2[((size_t)(s * D2 + c2) * D1 + c1) * 3 + dl];
    }
    __syncthreads();

    // ---- Phase 1: conv1 + gelu for 4 channels of this bi ----
#pragma unroll
    for (int k = 0; k < 4; ++k) {
        const int c1 = ci * 4 + k;
        const float wa = sw1[c1 * 3 + 0], wb = sw1[c1 * 3 + 1], wc = sw1[c1 * 3 + 2];
        const float bb = sb1[c1];
        bf16x8 pk;
#pragma unroll
        for (int l = 0; l < L_; ++l) {
            float v = fmaf(wa, xv[l], fmaf(wb, xv[l + 1], fmaf(wc, xv[l + 2], bb)));
            pk[l] = f2bf(gelu_fast(v));
        }
        pk[5] = 0; pk[6] = 0; pk[7] = 0;
        *(bf16x8*)&sh1[bi * 264 + c1 * 8] = pk;
    }
    __syncthreads();

    // ---- Phase 2: conv2 + gelu for 8 channels c2 = ci*8 + j ----
    float acc[8][5];
#pragma unroll
    for (int j = 0; j < 8; ++j) {
        const float bb = sb2[ci * 8 + j];
#pragma unroll
        for (int l = 0; l < 5; ++l) acc[j][l] = bb;
    }

#pragma unroll 2
    for (int c1 = 0; c1 < D1; ++c1) {
        bf16x8 hv = *(const bf16x8*)&sh1[bi * 264 + c1 * 8];
        const float p0 = bf2f(hv[0]), p1 = bf2f(hv[1]), p2 = bf2f(hv[2]),
                    p3 = bf2f(hv[3]), p4 = bf2f(hv[4]);
        const float* wbase = &sw2T[c1 * 3 * 64 + ci * 8];
        f32x4 w0a = *(const f32x4*)(wbase + 0 * 64);
        f32x4 w0b = *(const f32x4*)(wbase + 0 * 64 + 4);
        f32x4 w1a = *(const f32x4*)(wbase + 1 * 64);
        f32x4 w1b = *(const f32x4*)(wbase + 1 * 64 + 4);
        f32x4 w2a = *(const f32x4*)(wbase + 2 * 64);
        f32x4 w2b = *(const f32x4*)(wbase + 2 * 64 + 4);
#pragma unroll
        for (int j = 0; j < 8; ++j) {
            const float wA = (j < 4) ? w0a[j & 3] : w0b[j & 3];
            const float wB = (j < 4) ? w1a[j & 3] : w1b[j & 3];
            const float wC = (j < 4) ? w2a[j & 3] : w2b[j & 3];
            acc[j][0] = fmaf(wB, p0, fmaf(wC, p1, acc[j][0]));
            acc[j][1] = fmaf(wA, p0, fmaf(wB, p1, fmaf(wC, p2, acc[j][1])));
            acc[j][2] = fmaf(wA, p1, fmaf(wB, p2, fmaf(wC, p3, acc[j][2])));
            acc[j][3] = fmaf(wA, p2, fmaf(wB, p3, fmaf(wC, p4, acc[j][3])));
            acc[j][4] = fmaf(wA, p3, fmaf(wB, p4, acc[j][4]));
        }
    }

    // gelu, quantize, stats, store
    bf16x8 hbv[5];
    float su[8], sq[8];
#pragma unroll
    for (int j = 0; j < 8; ++j) { su[j] = 0.f; sq[j] = 0.f; }
#pragma unroll
    for (int t = 0; t < 5; ++t) {
#pragma unroll
        for (int e = 0; e < 8; ++e) {
            const int idx = t * 8 + e;
            const int j = idx / 5, l = idx % 5;
            float g = gelu_fast(acc[j][l]);
            short hb = f2bf(g);
            hbv[t][e] = hb;
            float gq = bf2f(hb);
            su[j] += gq;
            sq[j] = fmaf(gq, gq, sq[j]);
        }
    }
    bf16x8* dst = (bf16x8*)(H + ((size_t)s * B_ + b) * KDIM + ci * 40);
#pragma unroll
    for (int t = 0; t < 5; ++t) dst[t] = hbv[t];

#pragma unroll
    for (int j = 0; j < 8; ++j) {
        su[j] += __shfl_down(su[j], 32); sq[j] += __shfl_down(sq[j], 32);
        su[j] += __shfl_down(su[j], 16); sq[j] += __shfl_down(sq[j], 16);
        su[j] += __shfl_down(su[j], 8);  sq[j] += __shfl_down(sq[j], 8);
    }
    const int wid = tid >> 6;
    const int lane = tid & 63;
    if (lane < 8) {
#pragma unroll
        for (int j = 0; j < 8; ++j) {
            sred[wid][lane][j] = su[j];
            sred[wid][lane][8 + j] = sq[j];
        }
    }
    __syncthreads();
    if (tid < 128) {
        const int which = tid >> 6;
        const int c2 = tid & 63;
        const int rci = c2 >> 3, rj = c2 & 7;
        float v = sred[0][rci][which * 8 + rj] + sred[1][rci][which * 8 + rj]
                + sred[2][rci][which * 8 + rj] + sred[3][rci][which * 8 + rj];
        atomicAdd(&stats[(s * D2 + c2) * 2 + which], v);
    }
}

// ---------------------------------------------------------------------------
__global__ void k_stats(const float* __restrict__ stats,
                        const float* __restrict__ gamma, const float* __restrict__ beta,
                        float* __restrict__ af, float* __restrict__ cf)
{
    int i = threadIdx.x;
    if (i < S_ * D2) {
        const float n = (float)B_ * (float)L_;
        float su = stats[i * 2 + 0], sq = stats[i * 2 + 1];
        float mean = su / n;
        float var = sq / n - mean * mean;
        float rstd = rsqrtf(var + EPS_);
        float a = gamma[i] * rstd;
        af[i] = a;
        cf[i] = beta[i] - mean * a;
    }
}

// ---------------------------------------------------------------------------
__global__ __launch_bounds__(64) void k_fold(
    const float* __restrict__ wl, const float* __restrict__ bl,
    const float* __restrict__ af, const float* __restrict__ cf,
    __hip_bfloat16* __restrict__ Wp, float* __restrict__ blp)
{
    const int row = blockIdx.x;
    const int s = row / OUT_PAD, o = row % OUT_PAD;
    const int lane = threadIdx.x;
    __hip_bfloat16* wrow = Wp + (size_t)row * KDIM;
    if (o >= OUT_N) {
#pragma unroll
        for (int t = 0; t < 5; ++t) wrow[lane * 5 + t] = __float2bfloat16(0.f);
        if (lane == 0) blp[row] = 0.f;
        return;
    }
    const float* wsrc = wl + ((size_t)s * OUT_N + o) * KDIM;
    const float a = af[s * D2 + lane];
    const float c = cf[s * D2 + lane];
    float bacc = 0.f;
#pragma unroll
    for (int t = 0; t < 5; ++t) {
        float wv = wsrc[lane * 5 + t];
        wrow[lane * 5 + t] = __float2bfloat16(wv * a);
        bacc = fmaf(wv, c, bacc);
    }
#pragma unroll
    for (int off = 32; off > 0; off >>= 1) bacc += __shfl_down(bacc, off);
    if (lane == 0) blp[row] = bacc + bl[s * OUT_N + o];
}

// ---------------------------------------------------------------------------
// Kernel 3 v3: bf16 MFMA GEMM, LDS-staged A (async global_load_lds,
// double-buffered, XOR-swizzled), tile 128M x 64N, K chunks of 64.
// ---------------------------------------------------------------------------
__global__ __launch_bounds__(256, 4) void k_gemm(
    const __hip_bfloat16* __restrict__ H, const __hip_bfloat16* __restrict__ Wp,
    const float* __restrict__ blp, float* __restrict__ out)
{
    const int s    = blockIdx.z;
    const int bm   = blockIdx.x * 128;
    const int bn   = blockIdx.y * 64;
    const int tid  = threadIdx.x;
    const int wave = tid >> 6;
    const int lane = tid & 63;
    const int lm   = lane & 15;
    const int quad = lane >> 4;

    // sA slot (row, kc) holds global (row, kc ^ (row&7)); kc = 16B chunk of K
    __shared__ __align__(16) short sA[2][128 * 64];

    const short* Hs = (const short*)H + (size_t)s * B_ * KDIM;
    const short* Bp = (const short*)Wp + ((size_t)s * OUT_PAD + bn) * KDIM;

    const int kcd = tid & 7;          // dest k-chunk (0..7) within a 64-k buffer
    const int rsub = tid >> 3;        // 0..31

#define STAGE(c, bufi)                                                          \
    {                                                                           \
        _Pragma("unroll")                                                       \
        for (int i = 0; i < 4; ++i) {                                           \
            const int row = i * 32 + rsub;                                      \
            const int kcs = kcd ^ (row & 7);                                    \
            cp16(&sA[bufi][row * 64 + kcd * 8],                                 \
                 Hs + (size_t)(bm + row) * KDIM + (c) * 64 + kcs * 8);          \
        }                                                                       \
    }

    f32x4 acc[2][4];
#pragma unroll
    for (int i = 0; i < 2; ++i)
#pragma unroll
        for (int j = 0; j < 4; ++j) acc[i][j] = (f32x4){0.f, 0.f, 0.f, 0.f};

    STAGE(0, 0);

    for (int c = 0; c < 5; ++c) {
        __syncthreads();                    // drains vmcnt -> buf[c&1] ready
        if (c + 1 < 5) STAGE(c + 1, (c + 1) & 1);   // async prefetch overlaps compute

        const short* buf = sA[c & 1];
        // A fragments: global (row, k = c*64 + s2*32 + quad*8)
        bf16x8 af[2][2];
#pragma unroll
        for (int mt = 0; mt < 2; ++mt) {
#pragma unroll
            for (int s2 = 0; s2 < 2; ++s2) {
                const int row = wave * 32 + mt * 16 + lm;
                const int kc = s2 * 4 + quad;
                af[mt][s2] = *(const bf16x8*)&buf[row * 64 + (kc ^ (row & 7)) * 8];
            }
        }
#pragma unroll
        for (int s2 = 0; s2 < 2; ++s2) {
#pragma unroll
            for (int nt = 0; nt < 4; ++nt) {
                bf16x8 bf = *(const bf16x8*)(Bp + (size_t)(nt * 16 + lm) * KDIM
                                             + c * 64 + s2 * 32 + quad * 8);
                acc[0][nt] = __builtin_amdgcn_mfma_f32_16x16x32_bf16(af[0][s2], bf, acc[0][nt], 0, 0, 0);
                acc[1][nt] = __builtin_amdgcn_mfma_f32_16x16x32_bf16(af[1][s2], bf, acc[1][nt], 0, 0, 0);
            }
        }
    }
#undef STAGE

#pragma unroll
    for (int nt = 0; nt < 4; ++nt) {
        const int col = bn + nt * 16 + lm;
        const float bias = blp[s * OUT_PAD + col];
        if (col < OUT_N) {
#pragma unroll
            for (int mt = 0; mt < 2; ++mt) {
                const int row0 = bm + wave * 32 + mt * 16 + quad * 4;
#pragma unroll
                for (int r = 0; r < 4; ++r) {
                    out[((size_t)(row0 + r) * S_ + s) * OUT_N + col] = acc[mt][nt][r] + bias;
                }
            }
        }
    }
}

// ---------------------------------------------------------------------------
extern "C" void kernel_launch(void* const* d_in, const int* in_sizes, int n_in,
                              void* d_out, int out_size, void* d_ws, size_t ws_size,
                              hipStream_t stream) {
    const float* x     = (const float*)d_in[0];
    const float* w1    = (const float*)d_in[1];
    const float* b1    = (const float*)d_in[2];
    const float* w2    = (const float*)d_in[3];
    const float* b2    = (const float*)d_in[4];
    const float* gamma = (const float*)d_in[5];
    const float* beta  = (const float*)d_in[6];
    const float* wl    = (const float*)d_in[7];
    const float* bl    = (const float*)d_in[8];
    float* out = (float*)d_out;

    char* ws = (char*)d_ws;
    __hip_bfloat16* H = (__hip_bfloat16*)ws;
    size_t offH = (size_t)S_ * B_ * KDIM * sizeof(__hip_bfloat16);
    float* stats = (float*)(ws + offH);
    float* af = stats + S_ * D2 * 2;
    float* cf = af + S_ * D2;
    __hip_bfloat16* Wp = (__hip_bfloat16*)(cf + S_ * D2);
    float* blp = (float*)((char*)Wp + (size_t)S_ * OUT_PAD * KDIM * sizeof(__hip_bfloat16));

    hipMemsetAsync(stats, 0, (size_t)S_ * D2 * 2 * sizeof(float), stream);

    k_feat<<<dim3(B_ / 32, S_), 256, 0, stream>>>(x, w1, b1, w2, b2, H, stats);
    k_stats<<<1, 256, 0, stream>>>(stats, gamma, beta, af, cf);
    k_fold<<<S_ * OUT_PAD, 64, 0, stream>>>(wl, bl, af, cf, Wp, blp);
    k_gemm<<<dim3(B_ / 128, OUT_PAD / 64, S_), 256, 0, stream>>>(H, Wp, blp, out);
}